// Round 4
// baseline (23.867 us; speedup 1.0000x reference)
//
#include <hip/hip_runtime.h>
#include <float.h>

// Problem constants (from reference)
#define NB 5                    // N_BANDS
#define BB 256                  // B
#define LL 800                  // L
#define TT (NB * LL)            // 4000 values per batch row
#define NN (TT - NB)            // 3995 output diffs per row

constexpr int BPR  = 4;           // blocks per row (value-range quarters)
constexpr int THR  = 256;         // threads per block (4 waves)
constexpr int NBUK = 1024;        // local buckets per block
constexpr int GBUK = NBUK * BPR;  // 4096 global buckets
constexpr int EPT  = 16;          // full-row elements per thread (16*256=4096>=4000)
constexpr int BPT  = NBUK / THR;  // 4 buckets per thread in the scan
constexpr int CAP  = 2048;        // per-block element capacity (mean ~1000, sigma ~27)

__global__ __launch_bounds__(THR, 4)
void range_split_sort_diff(const float* __restrict__ in,
                           const int* __restrict__ ntotal,
                           float* __restrict__ out)
{
    __shared__ float scat[CAP];     // bucket-grouped (unordered within bucket)
    __shared__ float srt[CAP];      // sorted slice for this value range
    __shared__ int   cnt[NBUK];     // histogram -> scatter cursor -> bucket end
    __shared__ int   bstart[NBUK];  // bucket begin
    __shared__ int   wsum[4];       // per-wave scan totals
    __shared__ int   wcb[4];        // per-wave below-counts
    __shared__ float wpm[4];        // per-wave below-max

    const int blk  = blockIdx.x;
    const int b    = blk >> 2;      // row
    const int h    = blk & 3;       // value-range quarter
    const int tid  = threadIdx.x;
    const int lane = tid & 63;
    const int wid  = tid >> 6;
    const int gbase = h * NBUK;     // first global bucket owned by this block

    #pragma unroll
    for (int k = 0; k < BPT; ++k) cnt[tid + k * THR] = 0;
    __syncthreads();

    // ---- Phase 1: load FULL row; histogram own-range; count/max of below-range.
    float v[EPT];
    int   myg[EPT];
    int   cb = 0;
    float pm = -FLT_MAX;
    const float scale = (float)GBUK / 1000.0f;   // monotone bucket map, values in [0,1000)
    #pragma unroll
    for (int k = 0; k < EPT; ++k) {
        int j = tid + k * THR;
        if (j < TT) {
            int band = j / LL;
            int l    = j - band * LL;
            float x  = in[(band * BB + b) * LL + l];
            int g    = (int)(x * scale);
            g = g < 0 ? 0 : (g > GBUK - 1 ? GBUK - 1 : g);
            v[k]   = x;
            myg[k] = g;
            if (g < gbase) { ++cb; pm = fmaxf(pm, x); }
            else if ((g >> 10) == h) atomicAdd(&cnt[g & (NBUK - 1)], 1);
        } else { myg[k] = -1; v[k] = 0.0f; }
    }
    // block-reduce below-count (sum) and below-max
    #pragma unroll
    for (int d = 1; d < 64; d <<= 1) {
        cb += __shfl_xor(cb, d);
        pm  = fmaxf(pm, __shfl_xor(pm, d));
    }
    if (lane == 0) { wcb[wid] = cb; wpm[wid] = pm; }
    __syncthreads();   // also orders the histogram atomics
    const int   below = wcb[0] + wcb[1] + wcb[2] + wcb[3];
    const float pred  = fmaxf(fmaxf(wpm[0], wpm[1]), fmaxf(wpm[2], wpm[3]));

    // ---- Phase 2: exclusive prefix sum over 1024 local buckets.
    int c[BPT];
    int s = 0;
    #pragma unroll
    for (int k = 0; k < BPT; ++k) { c[k] = cnt[BPT * tid + k]; s += c[k]; }
    int inc = s;
    #pragma unroll
    for (int d = 1; d < 64; d <<= 1) {
        int t = __shfl_up(inc, d);
        if (lane >= d) inc += t;
    }
    if (lane == 63) wsum[wid] = inc;
    __syncthreads();
    int wo = 0;
    #pragma unroll
    for (int w = 0; w < 4; ++w) if (w < wid) wo += wsum[w];
    int run = (inc - s) + wo;
    #pragma unroll
    for (int k = 0; k < BPT; ++k) {
        bstart[BPT * tid + k] = run;
        cnt[BPT * tid + k]    = run;    // becomes scatter cursor
        run += c[k];
    }
    const int m = wsum[0] + wsum[1] + wsum[2] + wsum[3];  // elements in this range
    __syncthreads();

    // ---- Phase 3: scatter own-range values into bucket-grouped positions.
    int pos[EPT];
    #pragma unroll
    for (int k = 0; k < EPT; ++k) {
        pos[k] = -1;
        if (myg[k] >= 0 && (myg[k] >> 10) == h) {
            int p = atomicAdd(&cnt[myg[k] & (NBUK - 1)], 1);
            if (p < CAP) scat[p] = v[k];
            pos[k] = p;
        }
    }
    __syncthreads();

    // ---- Phase 4: parallel rank-count within bucket (scatter pos = tie-break).
    #pragma unroll
    for (int k = 0; k < EPT; ++k) {
        if (pos[k] >= 0) {
            int bkt = myg[k] & (NBUK - 1);
            int lo  = bstart[bkt];
            int hi  = cnt[bkt];
            float x = v[k];
            int   p = pos[k];
            int   r = lo;
            for (int j = lo; j < hi; ++j) {
                float w = scat[j];
                if (w < x || (w == x && j < p)) ++r;
            }
            if (r < CAP) srt[r] = x;
        }
    }
    __syncthreads();

    // ---- Phase 5: diffs for this contiguous slice of the global sort.
    // Global index of local r is g = below + r; out[i] = S[i+5]-S[i+4] -> i = g-5.
    const int nt = ntotal[b];
    for (int r = tid; r < m; r += THR) {
        int i = below + r - NB;
        if (i >= 0 && i < NN) {
            float left = (r > 0) ? srt[r - 1] : pred;
            float d    = srt[r] - left;
            out[b * NN + i] = (i < nt) ? d : 0.0f;
        }
    }
}

extern "C" void kernel_launch(void* const* d_in, const int* in_sizes, int n_in,
                              void* d_out, int out_size, void* d_ws, size_t ws_size,
                              hipStream_t stream) {
    const float* in  = (const float*)d_in[0];   // (5, 256, 800) fp32
    const int*   nt  = (const int*)d_in[1];     // (256,) int32
    float*       out = (float*)d_out;           // (256, 3995) fp32
    (void)in_sizes; (void)n_in; (void)out_size; (void)d_ws; (void)ws_size;
    range_split_sort_diff<<<BB * BPR, THR, 0, stream>>>(in, nt, out);
}

// Round 5
// 11.488 us; speedup vs baseline: 2.0775x; 2.0775x over previous
//
#include <hip/hip_runtime.h>
#include <float.h>

// Problem constants (from reference)
#define NB 5                    // N_BANDS
#define BB 256                  // B
#define LL 800                  // L
#define TT (NB * LL)            // 4000 values per batch row
#define NN (TT - NB)            // 3995 output diffs per row

constexpr int BLOCK = 1024;     // 16 waves, one block per row
constexpr int NBUK  = 4096;     // lambda ~= 0.98
constexpr int BPT   = NBUK / BLOCK;  // 4 buckets per thread in the scan
constexpr int NV    = TT / 4;   // 1000 float4-loader threads (exactly covers row)

__global__ __launch_bounds__(BLOCK)
void bucket_rank_diff2(const float* __restrict__ in,
                       const int* __restrict__ ntotal,
                       float* __restrict__ out)
{
    __shared__ float scat[TT];          // bucket-grouped values
    __shared__ float srt[TT];           // fully sorted
    __shared__ int   cnt[NBUK];         // histogram (atomic, returns in-bucket offset)
    __shared__ int   bstart[NBUK + 1];  // bucket begin; bstart[NBUK] = TT sentinel
    __shared__ int   wsum[16];          // per-wave scan totals

    const int b    = blockIdx.x;
    const int tid  = threadIdx.x;
    const int lane = tid & 63;
    const int wid  = tid >> 6;

    #pragma unroll
    for (int k = 0; k < BPT; ++k) cnt[tid + k * BLOCK] = 0;
    __syncthreads();

    // ---- Phase 1: one float4 load per thread; histogram atomic RETURNS the
    //      within-bucket offset (this replaces the old separate scatter-atomic pass).
    float v[4];
    int   g[4];
    int   off[4];
    const bool active = (tid < NV);     // 1000 threads x 4 elements = 4000 exactly
    if (active) {
        int band = tid / 200;           // 200 float4 per (band,row) chunk of 800 floats
        int l4   = tid - band * 200;
        const float4* p = reinterpret_cast<const float4*>(in + (band * BB + b) * LL) + l4;
        float4 x4 = *p;                 // 16B aligned: (band*256+b)*3200 bytes
        v[0] = x4.x; v[1] = x4.y; v[2] = x4.z; v[3] = x4.w;
        const float scale = (float)NBUK / 1000.0f;   // monotone map, values in [0,1000)
        #pragma unroll
        for (int k = 0; k < 4; ++k) {
            int gg = (int)(v[k] * scale);
            gg = gg < 0 ? 0 : (gg > NBUK - 1 ? NBUK - 1 : gg);
            g[k]   = gg;
            off[k] = atomicAdd(&cnt[gg], 1);   // in-bucket arrival order
        }
    }
    __syncthreads();

    // ---- Phase 2: exclusive prefix sum over 4096 bucket counts (1 barrier).
    int c[BPT];
    int s = 0;
    #pragma unroll
    for (int k = 0; k < BPT; ++k) { c[k] = cnt[BPT * tid + k]; s += c[k]; }
    int inc = s;
    #pragma unroll
    for (int d = 1; d < 64; d <<= 1) {
        int t = __shfl_up(inc, d);
        if (lane >= d) inc += t;
    }
    if (lane == 63) wsum[wid] = inc;
    __syncthreads();
    int wo = 0;                          // redundant per-thread wave-offset (LDS broadcast)
    #pragma unroll
    for (int w = 0; w < 16; ++w) wo += (w < wid) ? wsum[w] : 0;
    int run = (inc - s) + wo;
    #pragma unroll
    for (int k = 0; k < BPT; ++k) { bstart[BPT * tid + k] = run; run += c[k]; }
    if (tid == 0) bstart[NBUK] = TT;
    __syncthreads();

    // ---- Phase 3: deterministic scatter — NO atomics, position = bstart + off.
    int pos[4];
    if (active) {
        #pragma unroll
        for (int k = 0; k < 4; ++k) {
            pos[k] = bstart[g[k]] + off[k];
            scat[pos[k]] = v[k];
        }
    }
    __syncthreads();

    // ---- Phase 4: parallel rank-count within bucket (scatter pos = tie-break).
    if (active) {
        #pragma unroll
        for (int k = 0; k < 4; ++k) {
            int lo = bstart[g[k]];
            int hi = bstart[g[k] + 1];
            float x = v[k];
            int   p = pos[k];
            int   r = lo;
            for (int j = lo; j < hi; ++j) {
                float w = scat[j];
                if (w < x || (w == x && j < p)) ++r;
            }
            srt[r] = x;
        }
    }
    __syncthreads();

    // ---- Phase 5: adjacent diffs of sorted[4:], masked, coalesced store.
    const int nt = ntotal[b];
    #pragma unroll
    for (int k = 0; k < 4; ++k) {
        int i = tid + k * BLOCK;
        if (i < NN) {
            float d = srt[i + NB] - srt[i + NB - 1];
            out[b * NN + i] = (i < nt) ? d : 0.0f;
        }
    }
}

extern "C" void kernel_launch(void* const* d_in, const int* in_sizes, int n_in,
                              void* d_out, int out_size, void* d_ws, size_t ws_size,
                              hipStream_t stream) {
    const float* in  = (const float*)d_in[0];   // (5, 256, 800) fp32
    const int*   nt  = (const int*)d_in[1];     // (256,) int32
    float*       out = (float*)d_out;           // (256, 3995) fp32
    (void)in_sizes; (void)n_in; (void)out_size; (void)d_ws; (void)ws_size;
    bucket_rank_diff2<<<BB, BLOCK, 0, stream>>>(in, nt, out);
}